// Round 1
// baseline (3336.809 us; speedup 1.0000x reference)
//
#include <hip/hip_runtime.h>
#include <hip/hip_bf16.h>

// GCN 2-layer surrogate:
//   deg[i] = in-degree(i) + 1 (self-loop); dinv = rsqrt(deg)
//   hs  = dinv[r] * (x @ W1)          (pre-scaled by src factor)
//   out1 = relu(dinv[i]*(sum_{e:dst=i} hs[src] + hs[i]) + b1)
//   hs2 = dinv[i] * (out1 @ W2)
//   out  = dinv[i]*(sum hs2[src] + hs2[i]) + b2

#define N_NODES 100000
#define IN_DIM 128
#define HID_DIM 64
#define OUT_DIM 2

// ---------------- degree histogram ----------------
__global__ __launch_bounds__(256) void deg_kernel(const int* __restrict__ dst,
                                                  int* __restrict__ cnt, int E) {
    int e = blockIdx.x * 256 + threadIdx.x;
    if (e < E) atomicAdd(&cnt[dst[e]], 1);
}

__global__ __launch_bounds__(256) void dinv_kernel(const int* __restrict__ cnt,
                                                   float* __restrict__ dinv, int n) {
    int i = blockIdx.x * 256 + threadIdx.x;
    if (i < n) dinv[i] = rsqrtf((float)cnt[i] + 1.0f);
}

// ---------------- GEMM1: hs = dinv[r] * (x @ W1), 100000x128 @ 128x64 ----------------
// 64 rows x 64 cols per block, 4x4 per thread, K=128 staged in LDS.
__global__ __launch_bounds__(256) void gemm1_kernel(const float* __restrict__ x,
                                                    const float* __restrict__ W1,
                                                    const float* __restrict__ dinv,
                                                    float* __restrict__ hs, int n) {
    __shared__ float sW[IN_DIM * HID_DIM];   // [k][c], 32 KB
    __shared__ float sX[64 * 132];           // [r][k], stride 132 (16B-aligned, fewer conflicts)
    const int tid = threadIdx.x;
    const int rbase = blockIdx.x * 64;

#pragma unroll
    for (int i = 0; i < 32; ++i) sW[tid + i * 256] = W1[tid + i * 256];
#pragma unroll
    for (int j = 0; j < 32; ++j) {
        int idx = tid + j * 256;          // 0..8191
        int r = idx >> 7, k = idx & 127;
        int gr = rbase + r;
        sX[r * 132 + k] = (gr < n) ? x[gr * IN_DIM + k] : 0.0f;
    }
    __syncthreads();

    const int tx = tid & 15, ty = tid >> 4;
    const int c0 = tx * 4, r0 = ty * 4;
    float acc[4][4] = {};

    for (int k0 = 0; k0 < IN_DIM; k0 += 4) {
        float as[4][4];
        float4 b[4];
#pragma unroll
        for (int i = 0; i < 4; ++i) {
            float4 av = *(const float4*)&sX[(r0 + i) * 132 + k0];
            as[i][0] = av.x; as[i][1] = av.y; as[i][2] = av.z; as[i][3] = av.w;
        }
#pragma unroll
        for (int kk = 0; kk < 4; ++kk) b[kk] = *(const float4*)&sW[(k0 + kk) * HID_DIM + c0];
#pragma unroll
        for (int i = 0; i < 4; ++i) {
#pragma unroll
            for (int kk = 0; kk < 4; ++kk) {
                acc[i][0] += as[i][kk] * b[kk].x;
                acc[i][1] += as[i][kk] * b[kk].y;
                acc[i][2] += as[i][kk] * b[kk].z;
                acc[i][3] += as[i][kk] * b[kk].w;
            }
        }
    }

#pragma unroll
    for (int i = 0; i < 4; ++i) {
        int r = rbase + r0 + i;
        if (r < n) {
            float di = dinv[r];
            float4 v = make_float4(acc[i][0] * di, acc[i][1] * di, acc[i][2] * di, acc[i][3] * di);
            *(float4*)&hs[r * HID_DIM + c0] = v;
        }
    }
}

// ---------------- scatter1: agg[dst] += hs[src], d=64 ----------------
// one thread = (edge, 4-float chunk); 16 threads per edge.
__global__ __launch_bounds__(256) void scatter1_kernel(const int* __restrict__ ei,
                                                       const float* __restrict__ hs,
                                                       float* __restrict__ agg, int E) {
    int idx = blockIdx.x * 256 + threadIdx.x;
    int total = E * 16;
    if (idx >= total) return;
    int e = idx >> 4;
    int q = idx & 15;
    int s = ei[e];
    int d = ei[E + e];
    float4 v = *(const float4*)&hs[s * HID_DIM + q * 4];
    float* o = &agg[d * HID_DIM + q * 4];
    unsafeAtomicAdd(o + 0, v.x);
    unsafeAtomicAdd(o + 1, v.y);
    unsafeAtomicAdd(o + 2, v.z);
    unsafeAtomicAdd(o + 3, v.w);
}

// ---------------- post1: relu + dense (64->2) + pre-scale ----------------
// one wave per node (64 lanes = 64 hidden dims).
__global__ __launch_bounds__(256) void post1_kernel(const float* __restrict__ agg,
                                                    const float* __restrict__ hs,
                                                    const float* __restrict__ dinv,
                                                    const float* __restrict__ b1,
                                                    const float* __restrict__ W2,
                                                    float* __restrict__ hs2, int n) {
    int node = blockIdx.x * 4 + (threadIdx.x >> 6);
    int lane = threadIdx.x & 63;
    if (node >= n) return;
    float di = dinv[node];
    float a = agg[node * HID_DIM + lane] + hs[node * HID_DIM + lane];
    float t = di * a + b1[lane];
    t = fmaxf(t, 0.0f);
    float p0 = t * W2[lane * OUT_DIM + 0];
    float p1 = t * W2[lane * OUT_DIM + 1];
#pragma unroll
    for (int off = 32; off > 0; off >>= 1) {
        p0 += __shfl_down(p0, off);
        p1 += __shfl_down(p1, off);
    }
    if (lane == 0) {
        hs2[node * OUT_DIM + 0] = di * p0;
        hs2[node * OUT_DIM + 1] = di * p1;
    }
}

// ---------------- scatter2: out[dst] += hs2[src], d=2 ----------------
__global__ __launch_bounds__(256) void scatter2_kernel(const int* __restrict__ ei,
                                                       const float* __restrict__ hs2,
                                                       float* __restrict__ out, int E) {
    int e = blockIdx.x * 256 + threadIdx.x;
    if (e >= E) return;
    int s = ei[e];
    int d = ei[E + e];
    float2 v = *(const float2*)&hs2[s * OUT_DIM];
    unsafeAtomicAdd(&out[d * OUT_DIM + 0], v.x);
    unsafeAtomicAdd(&out[d * OUT_DIM + 1], v.y);
}

// ---------------- post2: self-loop + dst scale + bias ----------------
__global__ __launch_bounds__(256) void post2_kernel(float* __restrict__ out,
                                                    const float* __restrict__ hs2,
                                                    const float* __restrict__ dinv,
                                                    const float* __restrict__ b2, int n) {
    int i = blockIdx.x * 256 + threadIdx.x;
    if (i >= n) return;
    float di = dinv[i];
    out[i * OUT_DIM + 0] = di * (out[i * OUT_DIM + 0] + hs2[i * OUT_DIM + 0]) + b2[0];
    out[i * OUT_DIM + 1] = di * (out[i * OUT_DIM + 1] + hs2[i * OUT_DIM + 1]) + b2[1];
}

extern "C" void kernel_launch(void* const* d_in, const int* in_sizes, int n_in,
                              void* d_out, int out_size, void* d_ws, size_t ws_size,
                              hipStream_t stream) {
    const float* x  = (const float*)d_in[0];
    const int*   ei = (const int*)d_in[1];     // [2][E], row 0 = src, row 1 = dst
    const float* W1 = (const float*)d_in[2];
    const float* b1 = (const float*)d_in[3];
    const float* W2 = (const float*)d_in[4];
    const float* b2 = (const float*)d_in[5];
    float* out = (float*)d_out;

    const int n = N_NODES;
    const int E = in_sizes[1] / 2;

    char* ws = (char*)d_ws;
    int*   cnt  = (int*)  (ws + 0);
    float* dinv = (float*)(ws + (1u << 20));
    float* hs   = (float*)(ws + (2u << 20));    // 25.6 MB
    float* agg  = (float*)(ws + (28u << 20));   // 25.6 MB
    float* hs2  = (float*)(ws + (56u << 20));   // 0.8 MB

    hipMemsetAsync(cnt, 0, (size_t)n * sizeof(int), stream);
    hipMemsetAsync(agg, 0, (size_t)n * HID_DIM * sizeof(float), stream);
    hipMemsetAsync(out, 0, (size_t)n * OUT_DIM * sizeof(float), stream);

    deg_kernel<<<(E + 255) / 256, 256, 0, stream>>>(ei + E, cnt, E);
    dinv_kernel<<<(n + 255) / 256, 256, 0, stream>>>(cnt, dinv, n);
    gemm1_kernel<<<(n + 63) / 64, 256, 0, stream>>>(x, W1, dinv, hs, n);
    {
        long long total = (long long)E * 16;
        int blocks = (int)((total + 255) / 256);
        scatter1_kernel<<<blocks, 256, 0, stream>>>(ei, hs, agg, E);
    }
    post1_kernel<<<(n + 3) / 4, 256, 0, stream>>>(agg, hs, dinv, b1, W2, hs2, n);
    scatter2_kernel<<<(E + 255) / 256, 256, 0, stream>>>(ei, hs2, out, E);
    post2_kernel<<<(n + 255) / 256, 256, 0, stream>>>(out, hs2, dinv, b2, n);
}

// Round 2
// 706.701 us; speedup vs baseline: 4.7217x; 4.7217x over previous
//
#include <hip/hip_runtime.h>
#include <hip/hip_bf16.h>

// GCN 2-layer surrogate, CSR gather-reduce formulation (no f32 atomics):
//   deg[i] = in-degree(i) + 1 (self-loop); dinv = rsqrt(deg)
//   CSR: counting-sort edges by dst (rowptr via prefix sum, atomic-cursor fill)
//   hs   = dinv[r] * (x @ W1)                       (pre-scaled by src factor)
//   agg1: per node, acc = hs[i] + sum_{e: dst=i} hs[src]
//         t = relu(dinv[i]*acc + b1); hs2[i] = dinv[i] * (t @ W2)   (fused)
//   agg2: per node, out = dinv[i]*(hs2[i] + sum hs2[src]) + b2      (fused)

#define N_NODES 100000
#define IN_DIM 128
#define HID_DIM 64
#define OUT_DIM 2
#define SCAN_BLOCK 256

// ---------------- degree histogram ----------------
__global__ __launch_bounds__(256) void deg_kernel(const int* __restrict__ dst,
                                                  int* __restrict__ cnt, int E) {
    int e = blockIdx.x * 256 + threadIdx.x;
    if (e < E) atomicAdd(&cnt[dst[e]], 1);
}

__global__ __launch_bounds__(256) void dinv_kernel(const int* __restrict__ cnt,
                                                   float* __restrict__ dinv, int n) {
    int i = blockIdx.x * 256 + threadIdx.x;
    if (i < n) dinv[i] = rsqrtf((float)cnt[i] + 1.0f);
}

// ---------------- prefix sum (3-phase) ----------------
// A: per-block exclusive scan of cnt -> rowptr, block total -> blockSums[b]
__global__ __launch_bounds__(SCAN_BLOCK) void scanA_kernel(const int* __restrict__ cnt,
                                                           int* __restrict__ rowptr,
                                                           int* __restrict__ blockSums,
                                                           int n) {
    __shared__ int s[SCAN_BLOCK];
    int t = threadIdx.x;
    int i = blockIdx.x * SCAN_BLOCK + t;
    int v = (i < n) ? cnt[i] : 0;
    s[t] = v;
    __syncthreads();
#pragma unroll
    for (int off = 1; off < SCAN_BLOCK; off <<= 1) {
        int u = (t >= off) ? s[t - off] : 0;
        __syncthreads();
        s[t] += u;
        __syncthreads();
    }
    if (i < n) rowptr[i] = s[t] - v;              // exclusive within block
    if (t == SCAN_BLOCK - 1) blockSums[blockIdx.x] = s[t];
}

// B: single-block exclusive scan of blockSums (nb <= 512)
__global__ __launch_bounds__(512) void scanB_kernel(int* __restrict__ blockSums, int nb) {
    __shared__ int s[512];
    int t = threadIdx.x;
    int v = (t < nb) ? blockSums[t] : 0;
    s[t] = v;
    __syncthreads();
#pragma unroll
    for (int off = 1; off < 512; off <<= 1) {
        int u = (t >= off) ? s[t - off] : 0;
        __syncthreads();
        s[t] += u;
        __syncthreads();
    }
    if (t < nb) blockSums[t] = s[t] - v;          // exclusive
}

// C: add block offsets; init cursor
__global__ __launch_bounds__(SCAN_BLOCK) void scanC_kernel(int* __restrict__ rowptr,
                                                           const int* __restrict__ blockSums,
                                                           int* __restrict__ cursor, int n) {
    int i = blockIdx.x * SCAN_BLOCK + threadIdx.x;
    if (i < n) {
        int r = rowptr[i] + blockSums[blockIdx.x];
        rowptr[i] = r;
        cursor[i] = r;
    }
}

// ---------------- CSR fill: csr_src[pos(dst)] = src ----------------
__global__ __launch_bounds__(256) void fill_kernel(const int* __restrict__ ei,
                                                   int* __restrict__ cursor,
                                                   int* __restrict__ csr_src, int E) {
    int e = blockIdx.x * 256 + threadIdx.x;
    if (e >= E) return;
    int s = ei[e];
    int d = ei[E + e];
    int pos = atomicAdd(&cursor[d], 1);
    csr_src[pos] = s;
}

// ---------------- GEMM1: hs = dinv[r] * (x @ W1), 100000x128 @ 128x64 ----------------
__global__ __launch_bounds__(256) void gemm1_kernel(const float* __restrict__ x,
                                                    const float* __restrict__ W1,
                                                    const float* __restrict__ dinv,
                                                    float* __restrict__ hs, int n) {
    __shared__ float sW[IN_DIM * HID_DIM];   // [k][c], 32 KB
    __shared__ float sX[64 * 132];           // [r][k], stride 132
    const int tid = threadIdx.x;
    const int rbase = blockIdx.x * 64;

#pragma unroll
    for (int i = 0; i < 32; ++i) sW[tid + i * 256] = W1[tid + i * 256];
#pragma unroll
    for (int j = 0; j < 32; ++j) {
        int idx = tid + j * 256;
        int r = idx >> 7, k = idx & 127;
        int gr = rbase + r;
        sX[r * 132 + k] = (gr < n) ? x[gr * IN_DIM + k] : 0.0f;
    }
    __syncthreads();

    const int tx = tid & 15, ty = tid >> 4;
    const int c0 = tx * 4, r0 = ty * 4;
    float acc[4][4] = {};

    for (int k0 = 0; k0 < IN_DIM; k0 += 4) {
        float as[4][4];
        float4 b[4];
#pragma unroll
        for (int i = 0; i < 4; ++i) {
            float4 av = *(const float4*)&sX[(r0 + i) * 132 + k0];
            as[i][0] = av.x; as[i][1] = av.y; as[i][2] = av.z; as[i][3] = av.w;
        }
#pragma unroll
        for (int kk = 0; kk < 4; ++kk) b[kk] = *(const float4*)&sW[(k0 + kk) * HID_DIM + c0];
#pragma unroll
        for (int i = 0; i < 4; ++i) {
#pragma unroll
            for (int kk = 0; kk < 4; ++kk) {
                acc[i][0] += as[i][kk] * b[kk].x;
                acc[i][1] += as[i][kk] * b[kk].y;
                acc[i][2] += as[i][kk] * b[kk].z;
                acc[i][3] += as[i][kk] * b[kk].w;
            }
        }
    }

#pragma unroll
    for (int i = 0; i < 4; ++i) {
        int r = rbase + r0 + i;
        if (r < n) {
            float di = dinv[r];
            float4 v = make_float4(acc[i][0] * di, acc[i][1] * di, acc[i][2] * di, acc[i][3] * di);
            *(float4*)&hs[r * HID_DIM + c0] = v;
        }
    }
}

// ---------------- agg1 (fused): CSR gather-reduce + relu + (64->2) + pre-scale ----------------
// one wave per node; lane = hidden dim. Each edge is one coalesced 256B load.
__global__ __launch_bounds__(256) void agg1_kernel(const int* __restrict__ rowptr,
                                                   const int* __restrict__ cnt,
                                                   const int* __restrict__ csr_src,
                                                   const float* __restrict__ hs,
                                                   const float* __restrict__ dinv,
                                                   const float* __restrict__ b1,
                                                   const float* __restrict__ W2,
                                                   float* __restrict__ hs2, int n) {
    int node = blockIdx.x * 4 + (threadIdx.x >> 6);
    int lane = threadIdx.x & 63;
    if (node >= n) return;
    int start = rowptr[node];
    int deg = cnt[node];

    float acc = hs[node * HID_DIM + lane];        // self-loop term
    int j = 0;
    for (; j + 4 <= deg; j += 4) {
        int s0 = csr_src[start + j + 0];
        int s1 = csr_src[start + j + 1];
        int s2 = csr_src[start + j + 2];
        int s3 = csr_src[start + j + 3];
        float v0 = hs[s0 * HID_DIM + lane];
        float v1 = hs[s1 * HID_DIM + lane];
        float v2 = hs[s2 * HID_DIM + lane];
        float v3 = hs[s3 * HID_DIM + lane];
        acc += (v0 + v1) + (v2 + v3);
    }
    for (; j < deg; ++j) acc += hs[csr_src[start + j] * HID_DIM + lane];

    float di = dinv[node];
    float t = fmaxf(di * acc + b1[lane], 0.0f);
    float p0 = t * W2[lane * OUT_DIM + 0];
    float p1 = t * W2[lane * OUT_DIM + 1];
#pragma unroll
    for (int off = 32; off > 0; off >>= 1) {
        p0 += __shfl_down(p0, off);
        p1 += __shfl_down(p1, off);
    }
    if (lane == 0) {
        hs2[node * OUT_DIM + 0] = di * p0;
        hs2[node * OUT_DIM + 1] = di * p1;
    }
}

// ---------------- agg2 (fused): CSR gather-reduce d=2 + self-loop + scale + bias ----------------
// one wave per node; lane-parallel over edges, butterfly reduce.
__global__ __launch_bounds__(256) void agg2_kernel(const int* __restrict__ rowptr,
                                                   const int* __restrict__ cnt,
                                                   const int* __restrict__ csr_src,
                                                   const float* __restrict__ hs2,
                                                   const float* __restrict__ dinv,
                                                   const float* __restrict__ b2,
                                                   float* __restrict__ out, int n) {
    int node = blockIdx.x * 4 + (threadIdx.x >> 6);
    int lane = threadIdx.x & 63;
    if (node >= n) return;
    int start = rowptr[node];
    int deg = cnt[node];

    float a0 = 0.0f, a1 = 0.0f;
    for (int j = lane; j < deg; j += 64) {
        int s = csr_src[start + j];
        float2 v = *(const float2*)&hs2[s * OUT_DIM];
        a0 += v.x;
        a1 += v.y;
    }
#pragma unroll
    for (int off = 32; off > 0; off >>= 1) {
        a0 += __shfl_xor(a0, off);
        a1 += __shfl_xor(a1, off);
    }
    if (lane == 0) {
        float di = dinv[node];
        float2 self = *(const float2*)&hs2[node * OUT_DIM];
        out[node * OUT_DIM + 0] = di * (a0 + self.x) + b2[0];
        out[node * OUT_DIM + 1] = di * (a1 + self.y) + b2[1];
    }
}

extern "C" void kernel_launch(void* const* d_in, const int* in_sizes, int n_in,
                              void* d_out, int out_size, void* d_ws, size_t ws_size,
                              hipStream_t stream) {
    const float* x  = (const float*)d_in[0];
    const int*   ei = (const int*)d_in[1];     // [2][E], row 0 = src, row 1 = dst
    const float* W1 = (const float*)d_in[2];
    const float* b1 = (const float*)d_in[3];
    const float* W2 = (const float*)d_in[4];
    const float* b2 = (const float*)d_in[5];
    float* out = (float*)d_out;

    const int n = N_NODES;
    const int E = in_sizes[1] / 2;
    const int nScanBlocks = (n + SCAN_BLOCK - 1) / SCAN_BLOCK;   // 391

    char* ws = (char*)d_ws;
    int*   cnt       = (int*)  (ws + 0);               // 400 KB
    float* dinv      = (float*)(ws + (1u << 20));      // 400 KB
    int*   rowptr    = (int*)  (ws + (2u << 20));      // 400 KB
    int*   cursor    = (int*)  (ws + (3u << 20));      // 400 KB
    int*   blockSums = (int*)  (ws + (4u << 20));      // 2 KB
    float* hs        = (float*)(ws + (5u << 20));      // 25.6 MB
    int*   csr_src   = (int*)  (ws + (32u << 20));     // 12.8 MB
    float* hs2       = (float*)(ws + (46u << 20));     // 0.8 MB

    hipMemsetAsync(cnt, 0, (size_t)n * sizeof(int), stream);

    deg_kernel<<<(E + 255) / 256, 256, 0, stream>>>(ei + E, cnt, E);
    dinv_kernel<<<(n + 255) / 256, 256, 0, stream>>>(cnt, dinv, n);
    scanA_kernel<<<nScanBlocks, SCAN_BLOCK, 0, stream>>>(cnt, rowptr, blockSums, n);
    scanB_kernel<<<1, 512, 0, stream>>>(blockSums, nScanBlocks);
    scanC_kernel<<<nScanBlocks, SCAN_BLOCK, 0, stream>>>(rowptr, blockSums, cursor, n);
    fill_kernel<<<(E + 255) / 256, 256, 0, stream>>>(ei, cursor, csr_src, E);

    gemm1_kernel<<<(n + 63) / 64, 256, 0, stream>>>(x, W1, dinv, hs, n);
    agg1_kernel<<<(n + 3) / 4, 256, 0, stream>>>(rowptr, cnt, csr_src, hs, dinv, b1, W2, hs2, n);
    agg2_kernel<<<(n + 3) / 4, 256, 0, stream>>>(rowptr, cnt, csr_src, hs2, dinv, b2, out, n);
}

// Round 3
// 399.652 us; speedup vs baseline: 8.3493x; 1.7683x over previous
//
#include <hip/hip_runtime.h>
#include <hip/hip_bf16.h>

// GCN 2-layer surrogate, CSR gather-reduce with 2-level bucket sort CSR build.
//   bucket = dst >> 8  (391 buckets x 256 nodes)
//   hist:  global bucket histogram (LDS-merged)
//   bscan: scan bucket counts -> bucketStart, init gCursor
//   part:  bin 4096-edge chunks in LDS, claim per-(chunk,bucket) runs, write pairs coalesced
//   csr:   per bucket: LDS node-histogram (-> deg/dinv/rowptr) + scatter src into
//          L2-local 32KB region (full-line writebacks)
//   gemm1: hs = dinv[r] * (x @ W1)
//   agg1:  wave/node gather-reduce + relu + (64->2) + pre-scale  (fused)
//   agg2:  wave/node gather-reduce d=2 + self-loop + scale + bias (fused)

#define N_NODES 100000
#define IN_DIM 128
#define HID_DIM 64
#define OUT_DIM 2
#define NB 391          // ceil(100000/256) buckets
#define CHUNK 4096

// ---------------- A1: bucket histogram ----------------
__global__ __launch_bounds__(256) void hist_kernel(const int* __restrict__ dst,
                                                   int* __restrict__ gHist, int E) {
    __shared__ int h[NB];
    for (int i = threadIdx.x; i < NB; i += 256) h[i] = 0;
    __syncthreads();
    for (int e = blockIdx.x * 256 + threadIdx.x; e < E; e += gridDim.x * 256)
        atomicAdd(&h[dst[e] >> 8], 1);
    __syncthreads();
    for (int i = threadIdx.x; i < NB; i += 256)
        if (h[i]) atomicAdd(&gHist[i], h[i]);
}

// ---------------- B: scan bucket counts ----------------
__global__ __launch_bounds__(512) void bscan_kernel(const int* __restrict__ gHist,
                                                    int* __restrict__ bucketStart,
                                                    int* __restrict__ gCursor) {
    __shared__ int s[512];
    int t = threadIdx.x;
    int v = (t < NB) ? gHist[t] : 0;
    s[t] = v;
    __syncthreads();
#pragma unroll
    for (int off = 1; off < 512; off <<= 1) {
        int u = (t >= off) ? s[t - off] : 0;
        __syncthreads();
        s[t] += u;
        __syncthreads();
    }
    if (t < NB) {
        int st = s[t] - v;
        bucketStart[t] = st;
        gCursor[t] = st;
    }
}

// ---------------- A2: partition edges into bucket-ordered pairs ----------------
__global__ __launch_bounds__(512) void part_kernel(const int* __restrict__ ei,
                                                   int* __restrict__ gCursor,
                                                   int2* __restrict__ part, int E) {
    __shared__ int hist[512], lrow[512], gbase[512], lcur[512];
    __shared__ int lsrc[CHUNK], ldst[CHUNK];
    const int t = threadIdx.x;
    const int base = blockIdx.x * CHUNK;
    const int cntC = min(CHUNK, E - base);

    hist[t] = 0;
    __syncthreads();

    int s[8], d[8];
#pragma unroll
    for (int i = 0; i < 8; ++i) {
        int e = base + t + i * 512;
        if (e < E) {
            s[i] = ei[e];
            d[i] = ei[E + e];
            atomicAdd(&hist[d[i] >> 8], 1);
        }
    }
    __syncthreads();

    int v = hist[t];
    lrow[t] = v;
    __syncthreads();
#pragma unroll
    for (int off = 1; off < 512; off <<= 1) {
        int u = (t >= off) ? lrow[t - off] : 0;
        __syncthreads();
        lrow[t] += u;
        __syncthreads();
    }
    int excl = lrow[t] - v;
    if (t < NB && v > 0) gbase[t] = atomicAdd(&gCursor[t], v);
    lcur[t] = excl;
    lrow[t] = excl;                    // keep exclusive offsets for write-out
    __syncthreads();

#pragma unroll
    for (int i = 0; i < 8; ++i) {
        int e = base + t + i * 512;
        if (e < E) {
            int pos = atomicAdd(&lcur[d[i] >> 8], 1);
            lsrc[pos] = s[i];
            ldst[pos] = d[i];
        }
    }
    __syncthreads();

    for (int i = t; i < cntC; i += 512) {
        int dd = ldst[i];
        int b = dd >> 8;
        int g = gbase[b] + (i - lrow[b]);
        part[g] = make_int2(lsrc[i], dd);
    }
}

// ---------------- C: per-bucket CSR finalize (deg/dinv/rowptr + src scatter) ----------------
__global__ __launch_bounds__(256) void csr_kernel(const int2* __restrict__ part,
                                                  const int* __restrict__ gHist,
                                                  const int* __restrict__ bucketStart,
                                                  int* __restrict__ cnt,
                                                  float* __restrict__ dinv,
                                                  int* __restrict__ rowptr,
                                                  int* __restrict__ csr_src, int n) {
    __shared__ int lcnt[256], lrow[256], lcur[256];
    const int b = blockIdx.x, t = threadIdx.x;
    const int nodeBase = b << 8;
    const int start = bucketStart[b];
    const int count = gHist[b];

    lcnt[t] = 0;
    __syncthreads();
    for (int i = t; i < count; i += 256)
        atomicAdd(&lcnt[part[start + i].y & 255], 1);
    __syncthreads();

    int v = lcnt[t];
    lrow[t] = v;
    __syncthreads();
#pragma unroll
    for (int off = 1; off < 256; off <<= 1) {
        int u = (t >= off) ? lrow[t - off] : 0;
        __syncthreads();
        lrow[t] += u;
        __syncthreads();
    }
    int excl = lrow[t] - v;
    int node = nodeBase + t;
    if (node < n) {
        cnt[node] = v;
        dinv[node] = rsqrtf((float)v + 1.0f);
        rowptr[node] = start + excl;
    }
    lcur[t] = excl;
    __syncthreads();

    for (int i = t; i < count; i += 256) {
        int2 p = part[start + i];
        int pos = atomicAdd(&lcur[p.y & 255], 1);
        csr_src[start + pos] = p.x;
    }
}

// ---------------- GEMM1: hs = dinv[r] * (x @ W1), 100000x128 @ 128x64 ----------------
__global__ __launch_bounds__(256) void gemm1_kernel(const float* __restrict__ x,
                                                    const float* __restrict__ W1,
                                                    const float* __restrict__ dinv,
                                                    float* __restrict__ hs, int n) {
    __shared__ float sW[IN_DIM * HID_DIM];   // [k][c], 32 KB
    __shared__ float sX[64 * 132];           // [r][k], stride 132
    const int tid = threadIdx.x;
    const int rbase = blockIdx.x * 64;

#pragma unroll
    for (int i = 0; i < 32; ++i) sW[tid + i * 256] = W1[tid + i * 256];
#pragma unroll
    for (int j = 0; j < 32; ++j) {
        int idx = tid + j * 256;
        int r = idx >> 7, k = idx & 127;
        int gr = rbase + r;
        sX[r * 132 + k] = (gr < n) ? x[gr * IN_DIM + k] : 0.0f;
    }
    __syncthreads();

    const int tx = tid & 15, ty = tid >> 4;
    const int c0 = tx * 4, r0 = ty * 4;
    float acc[4][4] = {};

    for (int k0 = 0; k0 < IN_DIM; k0 += 4) {
        float as[4][4];
        float4 bv[4];
#pragma unroll
        for (int i = 0; i < 4; ++i) {
            float4 av = *(const float4*)&sX[(r0 + i) * 132 + k0];
            as[i][0] = av.x; as[i][1] = av.y; as[i][2] = av.z; as[i][3] = av.w;
        }
#pragma unroll
        for (int kk = 0; kk < 4; ++kk) bv[kk] = *(const float4*)&sW[(k0 + kk) * HID_DIM + c0];
#pragma unroll
        for (int i = 0; i < 4; ++i) {
#pragma unroll
            for (int kk = 0; kk < 4; ++kk) {
                acc[i][0] += as[i][kk] * bv[kk].x;
                acc[i][1] += as[i][kk] * bv[kk].y;
                acc[i][2] += as[i][kk] * bv[kk].z;
                acc[i][3] += as[i][kk] * bv[kk].w;
            }
        }
    }

#pragma unroll
    for (int i = 0; i < 4; ++i) {
        int r = rbase + r0 + i;
        if (r < n) {
            float di = dinv[r];
            float4 v = make_float4(acc[i][0] * di, acc[i][1] * di, acc[i][2] * di, acc[i][3] * di);
            *(float4*)&hs[r * HID_DIM + c0] = v;
        }
    }
}

// ---------------- agg1 (fused): CSR gather-reduce + relu + (64->2) + pre-scale ----------------
__global__ __launch_bounds__(256) void agg1_kernel(const int* __restrict__ rowptr,
                                                   const int* __restrict__ cnt,
                                                   const int* __restrict__ csr_src,
                                                   const float* __restrict__ hs,
                                                   const float* __restrict__ dinv,
                                                   const float* __restrict__ b1,
                                                   const float* __restrict__ W2,
                                                   float* __restrict__ hs2, int n) {
    int node = blockIdx.x * 4 + (threadIdx.x >> 6);
    int lane = threadIdx.x & 63;
    if (node >= n) return;
    int start = rowptr[node];
    int deg = cnt[node];

    float acc = hs[node * HID_DIM + lane];        // self-loop term
    int j = 0;
    for (; j + 4 <= deg; j += 4) {
        int s0 = csr_src[start + j + 0];
        int s1 = csr_src[start + j + 1];
        int s2 = csr_src[start + j + 2];
        int s3 = csr_src[start + j + 3];
        float v0 = hs[s0 * HID_DIM + lane];
        float v1 = hs[s1 * HID_DIM + lane];
        float v2 = hs[s2 * HID_DIM + lane];
        float v3 = hs[s3 * HID_DIM + lane];
        acc += (v0 + v1) + (v2 + v3);
    }
    for (; j < deg; ++j) acc += hs[csr_src[start + j] * HID_DIM + lane];

    float di = dinv[node];
    float t = fmaxf(di * acc + b1[lane], 0.0f);
    float p0 = t * W2[lane * OUT_DIM + 0];
    float p1 = t * W2[lane * OUT_DIM + 1];
#pragma unroll
    for (int off = 32; off > 0; off >>= 1) {
        p0 += __shfl_down(p0, off);
        p1 += __shfl_down(p1, off);
    }
    if (lane == 0) {
        hs2[node * OUT_DIM + 0] = di * p0;
        hs2[node * OUT_DIM + 1] = di * p1;
    }
}

// ---------------- agg2 (fused): CSR gather-reduce d=2 + self-loop + scale + bias ----------------
__global__ __launch_bounds__(256) void agg2_kernel(const int* __restrict__ rowptr,
                                                   const int* __restrict__ cnt,
                                                   const int* __restrict__ csr_src,
                                                   const float* __restrict__ hs2,
                                                   const float* __restrict__ dinv,
                                                   const float* __restrict__ b2,
                                                   float* __restrict__ out, int n) {
    int node = blockIdx.x * 4 + (threadIdx.x >> 6);
    int lane = threadIdx.x & 63;
    if (node >= n) return;
    int start = rowptr[node];
    int deg = cnt[node];

    float a0 = 0.0f, a1 = 0.0f;
    for (int j = lane; j < deg; j += 64) {
        int s = csr_src[start + j];
        float2 v = *(const float2*)&hs2[s * OUT_DIM];
        a0 += v.x;
        a1 += v.y;
    }
#pragma unroll
    for (int off = 32; off > 0; off >>= 1) {
        a0 += __shfl_xor(a0, off);
        a1 += __shfl_xor(a1, off);
    }
    if (lane == 0) {
        float di = dinv[node];
        float2 self = *(const float2*)&hs2[node * OUT_DIM];
        out[node * OUT_DIM + 0] = di * (a0 + self.x) + b2[0];
        out[node * OUT_DIM + 1] = di * (a1 + self.y) + b2[1];
    }
}

extern "C" void kernel_launch(void* const* d_in, const int* in_sizes, int n_in,
                              void* d_out, int out_size, void* d_ws, size_t ws_size,
                              hipStream_t stream) {
    const float* x  = (const float*)d_in[0];
    const int*   ei = (const int*)d_in[1];     // [2][E], row 0 = src, row 1 = dst
    const float* W1 = (const float*)d_in[2];
    const float* b1 = (const float*)d_in[3];
    const float* W2 = (const float*)d_in[4];
    const float* b2 = (const float*)d_in[5];
    float* out = (float*)d_out;

    const int n = N_NODES;
    const int E = in_sizes[1] / 2;

    char* ws = (char*)d_ws;
    int*   gHist       = (int*)  (ws + 0);            // 2 KB
    int*   bucketStart = (int*)  (ws + (4u << 10));   // 2 KB
    int*   gCursor     = (int*)  (ws + (8u << 10));   // 2 KB
    int*   cnt         = (int*)  (ws + (1u << 20));   // 400 KB
    float* dinv        = (float*)(ws + (2u << 20));   // 400 KB
    int*   rowptr      = (int*)  (ws + (3u << 20));   // 400 KB
    float* hs2         = (float*)(ws + (4u << 20));   // 800 KB
    int*   csr_src     = (int*)  (ws + (5u << 20));   // 12.8 MB
    // part (25.6 MB) and hs (25.6 MB) alias: part is fully consumed by csr_kernel
    // before gemm1_kernel writes hs.
    int2*  part        = (int2*) (ws + (18u << 20));
    float* hs          = (float*)(ws + (18u << 20));

    hipMemsetAsync(gHist, 0, NB * sizeof(int), stream);

    hist_kernel<<<1024, 256, 0, stream>>>(ei + E, gHist, E);
    bscan_kernel<<<1, 512, 0, stream>>>(gHist, bucketStart, gCursor);
    part_kernel<<<(E + CHUNK - 1) / CHUNK, 512, 0, stream>>>(ei, gCursor, part, E);
    csr_kernel<<<NB, 256, 0, stream>>>(part, gHist, bucketStart, cnt, dinv, rowptr, csr_src, n);

    gemm1_kernel<<<(n + 63) / 64, 256, 0, stream>>>(x, W1, dinv, hs, n);
    agg1_kernel<<<(n + 3) / 4, 256, 0, stream>>>(rowptr, cnt, csr_src, hs, dinv, b1, W2, hs2, n);
    agg2_kernel<<<(n + 3) / 4, 256, 0, stream>>>(rowptr, cnt, csr_src, hs2, dinv, b2, out, n);
}